// Round 2
// baseline (793.143 us; speedup 1.0000x reference)
//
#include <hip/hip_runtime.h>
#include <hip/hip_bf16.h>

// Problem constants
#define B_    8
#define DIM   256
#define HH    160
#define WW_   160
#define NHEAD 8
#define HD    32
#define P_    4
#define WP_   40      // windows per row/col (160/4)
#define NPW   1600    // windows per batch image (40*40)
#define PP    16      // tokens per window (4*4)

typedef __attribute__((ext_vector_type(8))) short bf16x8;
typedef __attribute__((ext_vector_type(4))) float f32x4;

__device__ __forceinline__ unsigned short f2b(float f) {
    __hip_bfloat16 h = __float2bfloat16(f);
    return *(unsigned short*)&h;
}

// Pre-convert out_w (fp32 [256][256]) -> bf16 in workspace.
__global__ void convert_w_kernel(const float* __restrict__ w,
                                 short* __restrict__ wb)
{
    const int i = blockIdx.x * 256 + threadIdx.x;   // 16384 threads, 4 elems each
    float4 v = ((const float4*)w)[i];
    short4 o;
    o.x = (short)f2b(v.x); o.y = (short)f2b(v.y);
    o.z = (short)f2b(v.z); o.w = (short)f2b(v.w);
    ((short4*)wb)[i] = o;
}

// One block = one (batch, window). 256 threads = 4 waves.
// Stage A: load x window (fp32), apply per-channel scale+bias -> q/k/v in LDS
// Stage B: 16x16 scores + bias + softmax (fp32)
// Stage C: attn @ v -> att tile [16 pos][256 c], stored bf16 in MFMA A-operand
//          swizzled layout
// Stage D: 1x1 conv via MFMA: Y[16 pos][256 o] = att @ out_w^T  (fp32 out)
__launch_bounds__(256, 2)
__global__ void patchsa_fused(const float* __restrict__ x,
                              const float* __restrict__ qkv_w,
                              const float* __restrict__ qkv_b,
                              const float* __restrict__ pos_encode,
                              const short* __restrict__ w_bf16,
                              const int* __restrict__ pos_index,
                              float* __restrict__ y)
{
    __shared__ float wql[768];
    __shared__ float bql[768];
    __shared__ float pel[392];        // pos_encode [49][8]
    __shared__ int   pil[256];        // pos_index [16][16]
    // q/k/v: [head][pos][d] with pitch 33: bank = (16*head + pos + d) % 32
    __shared__ float q4[NHEAD * 528];
    __shared__ float k4[NHEAD * 528];
    __shared__ float v4[NHEAD * 528];
    __shared__ float probs[2048];     // [head][i][j]
    // att tile, bf16, pre-swizzled into MFMA A-operand order:
    // element (m, k) at (k>>3)*128 + m*8 + (k&7)
    __shared__ alignas(16) short att3[4096];

    const int t   = threadIdx.x;
    const int blk = blockIdx.x;
    const int b   = blk / NPW;
    const int n   = blk % NPW;
    const int hp  = n / WP_;
    const int wp  = n % WP_;
    const int h0  = hp * P_;
    const int w0  = wp * P_;

    // ---- Stage 0: stage small params into LDS ----
    for (int idx = t; idx < 768; idx += 256) {
        wql[idx] = qkv_w[idx];
        bql[idx] = qkv_b[idx];
    }
    for (int idx = t; idx < 392; idx += 256)
        pel[idx] = pos_encode[idx];
    pil[t] = pos_index[t];
    __syncthreads();

    // ---- Stage A: load x window rows, compute q/k/v ----
    // 1024 tasks = 256 channels x 4 patch-rows; each task loads float4 (16B)
    for (int task = t; task < 1024; task += 256) {
        const int c  = task & 255;
        const int ph = task >> 8;
        const float* xr = x + ((((long)b * DIM + c) * HH) + h0 + ph) * WW_ + w0;
        float4 xv = *(const float4*)xr;
        const int head = c >> 5, d = c & 31;
        const float wq = wql[c],      bq = bql[c];
        const float wk = wql[256+c],  bk = bql[256+c];
        const float wv = wql[512+c],  bv = bql[512+c];
        const int base = head * 528 + d;
        const int p0 = ph * 4;
        float xf[4] = {xv.x, xv.y, xv.z, xv.w};
        #pragma unroll
        for (int pw = 0; pw < 4; ++pw) {
            const int off = base + (p0 + pw) * 33;
            q4[off] = xf[pw] * wq + bq;
            k4[off] = xf[pw] * wk + bk;
            v4[off] = xf[pw] * wv + bv;
        }
    }
    __syncthreads();

    // ---- Stage B: scores + bias + softmax (128 threads: (head, i)) ----
    if (t < 128) {
        const int head = t >> 4, i = t & 15;
        const float scale = 0.17677669529663687f; // 32^-0.5
        float qr[32];
        const int qb = head * 528 + i * 33;
        #pragma unroll
        for (int d = 0; d < 32; ++d) qr[d] = q4[qb + d];
        float s[16];
        #pragma unroll
        for (int j = 0; j < 16; ++j) {
            const int kb = head * 528 + j * 33;
            float acc = 0.f;
            #pragma unroll
            for (int d = 0; d < 32; ++d) acc += qr[d] * k4[kb + d];
            s[j] = acc * scale + pel[pil[i * 16 + j] * NHEAD + head];
        }
        float m = s[0];
        #pragma unroll
        for (int j = 1; j < 16; ++j) m = fmaxf(m, s[j]);
        float l = 0.f;
        #pragma unroll
        for (int j = 0; j < 16; ++j) { s[j] = __expf(s[j] - m); l += s[j]; }
        const float inv = 1.f / l;
        #pragma unroll
        for (int j = 0; j < 16; ++j)
            probs[(head * 16 + i) * 16 + j] = s[j] * inv;
    }
    __syncthreads();

    // ---- Stage C: P @ V -> att tile (256 threads: (head, d)) ----
    {
        const int head = t >> 5, d = t & 31;
        float vr[16];
        const int vb = head * 528 + d;
        #pragma unroll
        for (int j = 0; j < 16; ++j) vr[j] = v4[vb + j * 33];
        const int k = t;                      // channel == head*32 + d
        const int abase = (k >> 3) * 128 + (k & 7);
        #pragma unroll
        for (int i = 0; i < 16; ++i) {
            const float* pr = &probs[(head * 16 + i) * 16];
            float acc = 0.f;
            #pragma unroll
            for (int j = 0; j < 16; ++j) acc += pr[j] * vr[j];
            att3[abase + i * 8] = (short)f2b(acc);
        }
    }
    __syncthreads();

    // ---- Stage D: 1x1 conv via MFMA ----
    // Y[pos][o] = sum_c att[pos][c] * W[o][c]; per wave: 16x64 tile of Y
    {
        const int wave = t >> 6, lane = t & 63;
        const int m16  = lane & 15, kq = lane >> 4;
        const int nbase = wave * 64;
        f32x4 acc0 = {0.f, 0.f, 0.f, 0.f};
        f32x4 acc1 = acc0, acc2 = acc0, acc3 = acc0;
        #pragma unroll
        for (int kk = 0; kk < 8; ++kk) {
            const int k0 = kk * 32 + kq * 8;
            bf16x8 a = *(const bf16x8*)&att3[(k0 >> 3) * 128 + m16 * 8];
            bf16x8 b0 = *(const bf16x8*)&w_bf16[(nbase +  0 + m16) * 256 + k0];
            bf16x8 b1 = *(const bf16x8*)&w_bf16[(nbase + 16 + m16) * 256 + k0];
            bf16x8 b2 = *(const bf16x8*)&w_bf16[(nbase + 32 + m16) * 256 + k0];
            bf16x8 b3 = *(const bf16x8*)&w_bf16[(nbase + 48 + m16) * 256 + k0];
            acc0 = __builtin_amdgcn_mfma_f32_16x16x32_bf16(a, b0, acc0, 0, 0, 0);
            acc1 = __builtin_amdgcn_mfma_f32_16x16x32_bf16(a, b1, acc1, 0, 0, 0);
            acc2 = __builtin_amdgcn_mfma_f32_16x16x32_bf16(a, b2, acc2, 0, 0, 0);
            acc3 = __builtin_amdgcn_mfma_f32_16x16x32_bf16(a, b3, acc3, 0, 0, 0);
        }
        // Epilogue: D col = lane&15 (o within 16-tile), row = kq*4+reg (pos)
        f32x4 accs[4] = {acc0, acc1, acc2, acc3};
        #pragma unroll
        for (int nt = 0; nt < 4; ++nt) {
            const int o = nbase + nt * 16 + m16;
            const long ob = (((long)b * DIM + o) * HH) * WW_;
            #pragma unroll
            for (int r = 0; r < 4; ++r) {
                const int pos = kq * 4 + r;
                const int ph = pos >> 2, pw = pos & 3;
                y[ob + (long)(h0 + ph) * WW_ + (w0 + pw)] = accs[nt][r];
            }
        }
    }
}

extern "C" void kernel_launch(void* const* d_in, const int* in_sizes, int n_in,
                              void* d_out, int out_size, void* d_ws, size_t ws_size,
                              hipStream_t stream) {
    const float* x          = (const float*)d_in[0];
    const float* qkv_w      = (const float*)d_in[1];
    const float* qkv_b      = (const float*)d_in[2];
    const float* pos_encode = (const float*)d_in[3];
    const float* out_w      = (const float*)d_in[4];
    const int*   pos_index  = (const int*)d_in[5];
    float* y = (float*)d_out;
    short* w_bf16 = (short*)d_ws;

    convert_w_kernel<<<dim3(64), dim3(256), 0, stream>>>(out_w, w_bf16);
    patchsa_fused<<<dim3(B_ * NPW), dim3(256), 0, stream>>>(
        x, qkv_w, qkv_b, pos_encode, w_bf16, pos_index, y);
}